// Round 8
// baseline (94.434 us; speedup 1.0000x reference)
//
#include <hip/hip_runtime.h>
#include <hip/hip_bf16.h>

// Problem constants
#define B_ 2
#define N_ 48
#define H_ 256
#define NH_ 8
#define DH_ 32
#define KS_ 6      // k-slices per main block; grid = 96*(48/KS_) = 768
#define SQS_LD 100 // sqS row stride in floats (400B, 16B-aligned)

typedef __attribute__((ext_vector_type(8))) short bf16x8;
typedef __attribute__((ext_vector_type(4))) float f32x4;

__device__ __forceinline__ unsigned short f2bf(float f) {
  unsigned u = __float_as_uint(f);
  u += 0x7FFFu + ((u >> 16) & 1u);
  return (unsigned short)(u >> 16);
}

// pack 8 floats -> 8 bf16 (RNE) via v_cvt_pk_bf16_f32
__device__ __forceinline__ bf16x8 cvt8(float4 x, float4 y) {
  union { unsigned u[4]; bf16x8 v; } o;
  asm("v_cvt_pk_bf16_f32 %0, %1, %2" : "=v"(o.u[0]) : "v"(x.x), "v"(x.y));
  asm("v_cvt_pk_bf16_f32 %0, %1, %2" : "=v"(o.u[1]) : "v"(x.z), "v"(x.w));
  asm("v_cvt_pk_bf16_f32 %0, %1, %2" : "=v"(o.u[2]) : "v"(y.x), "v"(y.y));
  asm("v_cvt_pk_bf16_f32 %0, %1, %2" : "=v"(o.u[3]) : "v"(y.z), "v"(y.w));
  return o.v;
}

// Raw barrier WITHOUT vmcnt drain: keeps the triplet prefetch in flight
// across phases (__syncthreads would emit s_waitcnt vmcnt(0)).
__device__ __forceinline__ void bar_lgkm() {
  asm volatile("s_waitcnt lgkmcnt(0)" ::: "memory");
  __builtin_amdgcn_s_barrier();
  asm volatile("" ::: "memory");
}

// ---------------------------------------------------------------------------
// P0: pack weights into bf16 MFMA B-fragment order + bias concat.
// frag[nt][kt][lane][i] = W[kt*32 + (lane>>4)*8 + i][nt*16 + (lane&15)]
// ---------------------------------------------------------------------------
__global__ void pack_kernel(const float* __restrict__ Wq, const float* __restrict__ Wk,
                            const float* __restrict__ Wv, const float* __restrict__ bq,
                            const float* __restrict__ bk, const float* __restrict__ bv,
                            const float* __restrict__ Wsq, const float* __restrict__ Wsk,
                            const float* __restrict__ Wsv, const float* __restrict__ bsq,
                            const float* __restrict__ bsk, const float* __restrict__ bsv,
                            unsigned short* __restrict__ wfrag_pair,
                            unsigned short* __restrict__ wfrag_main,
                            float* __restrict__ biascat, float* __restrict__ biasm) {
  int t = blockIdx.x * 256 + threadIdx.x;
  if (t < 196608) {
    int i8 = t & 7, lane = (t >> 3) & 63, kt = (t >> 9) & 7, nt = t >> 12;
    int k = kt * 32 + ((lane >> 4) << 3) + i8;
    int n = nt * 16 + (lane & 15);
    const float* W = (n < 256) ? Wq : (n < 512) ? Wk : Wv;
    wfrag_pair[t] = f2bf(W[k * 256 + (n & 255)]);
  } else if (t < 196608 + 24576) {
    int p = t - 196608;
    int i8 = p & 7, lane = (p >> 3) & 63, kt = (p >> 9) & 7, nt = p >> 12;
    int k = kt * 32 + ((lane >> 4) << 3) + i8;
    int n = nt * 16 + (lane & 15);
    const float* W = (n < 32) ? Wsq : (n < 64) ? Wsk : Wsv;
    wfrag_main[p] = f2bf(W[k * 32 + (n & 31)]);
  } else if (t < 196608 + 24576 + 768) {
    int p = t - 196608 - 24576;
    const float* bsrc = (p < 256) ? bq : (p < 512) ? bk : bv;
    biascat[p] = bsrc[p & 255];
  } else if (t < 196608 + 24576 + 768 + 96) {
    int p = t - 196608 - 24576 - 768;
    biasm[p] = (p < 32) ? bsq[p] : (p < 64) ? bsk[p - 32] : bsv[p - 64];
  }
}

// ---------------------------------------------------------------------------
// LDS tile: bf16, byte = row*512 + col*2, XOR ^((row&7)<<4) both sides.
// ---------------------------------------------------------------------------
__device__ __forceinline__ void stage48x256(const float* __restrict__ src, char* tAc, int tid) {
#pragma unroll
  for (int it = 0; it < 4; ++it) {
    int c = it * 384 + tid;
    const float4* g = reinterpret_cast<const float4*>(src) + (c << 1);
    float4 x = g[0];
    float4 y = g[1];
    int row = c >> 5;
    int off = (row << 9) + ((c & 31) << 4);
    off ^= (row & 7) << 4;
    *reinterpret_cast<bf16x8*>(tAc + off) = cvt8(x, y);
  }
}

// ---------------------------------------------------------------------------
// A: pair projections.  proj[(b*48+i)*48+j][0:256]=q, [256:512]=k, [512:768]=v
// ---------------------------------------------------------------------------
__global__ __launch_bounds__(384, 3)
void pair_proj_kernel(const float* __restrict__ pair,
                      const unsigned short* __restrict__ wfrag_pair,
                      const float* __restrict__ biascat, float* __restrict__ proj) {
  __shared__ __align__(16) char tAc[48 * 256 * 2];
  int tid = threadIdx.x;
  int lane = tid & 63;
  int wave = tid >> 6;
  int gm = blockIdx.x >> 3;
  int gn = blockIdx.x & 7;

  stage48x256(pair + (size_t)gm * 12288, tAc, tid);

  bf16x8 wf[8];
  {
    const bf16x8* wp = reinterpret_cast<const bf16x8*>(wfrag_pair);
#pragma unroll
    for (int kt = 0; kt < 8; ++kt) wf[kt] = wp[((gn * 6 + wave) * 8 + kt) * 64 + lane];
  }
  __syncthreads();

  f32x4 acc[3];
#pragma unroll
  for (int mt = 0; mt < 3; ++mt) acc[mt] = (f32x4){0.f, 0.f, 0.f, 0.f};
#pragma unroll
  for (int kt = 0; kt < 8; ++kt) {
#pragma unroll
    for (int mt = 0; mt < 3; ++mt) {
      int row = mt * 16 + (lane & 15);
      int off = (row << 9) + (kt << 6) + ((lane >> 4) << 4);
      off ^= (row & 7) << 4;
      bf16x8 a = *reinterpret_cast<const bf16x8*>(tAc + off);
      acc[mt] = __builtin_amdgcn_mfma_f32_16x16x32_bf16(a, wf[kt], acc[mt], 0, 0, 0);
    }
  }

  int col = gn * 96 + wave * 16 + (lane & 15);
  float bias = biascat[col];
  int jb = (lane >> 4) * 4;
#pragma unroll
  for (int mt = 0; mt < 3; ++mt) {
#pragma unroll
    for (int rr = 0; rr < 4; ++rr) {
      int j = mt * 16 + jb + rr;
      proj[(size_t)(gm * 48 + j) * 768 + col] = acc[mt][rr] + bias;
    }
  }
}

// ---------------------------------------------------------------------------
// Main: one block per (b,i, 6 consecutive k); grid 768.  Cross-slice register
// prefetch of the 48x256 triplet tile; ALL compute phases are VMEM-free
// (q bf16 regs, wf regs, v/khl/mask in LDS) so nothing drains the prefetch.
// (384,2): honest VGPR allocation (~120-140); LDS 77.2KB -> 2 blocks/CU, so
// any VGPR <= 170 is occupancy-free.  4 raw lgkm barriers per slice.
// ---------------------------------------------------------------------------
__global__ __launch_bounds__(384, 2)
void e2e_main(const float* __restrict__ mask, const float* __restrict__ trip,
              const float* __restrict__ proj, const unsigned short* __restrict__ wfragm,
              const float* __restrict__ biasm, float* __restrict__ out) {
  __shared__ __align__(16) char tAc[48 * 256 * 2];        // 24576
  __shared__ __align__(16) float sqS[48 * SQS_LD];        // 19200 (j-major)
  __shared__ __align__(16) unsigned short vbf[48 * 256];  // 24576
  __shared__ float khlall[KS_][256];                      // 6144
  __shared__ float maskall[KS_][48];                      // 1152
  __shared__ float pbuf[8][48];                           // 1536  => 77184 B

  int tid = threadIdx.x;
  int lane = tid & 63;
  int wave = tid >> 6;

  int bid = blockIdx.x;
  int xcd = bid & 7;
  int slot = bid >> 3;
  int g = xcd * 12 + (slot >> 3);  // (b*48+i)
  int kg = slot & 7;
  int k0 = kg * KS_;
  int b = g / 48;
  int rowbase = g * 48;

  float biasn;
  {
    int n = wave * 16 + (lane & 15);
    biasn = biasm[n];
  }

  // ---- prologue: consumed-now loads first (q, v, khl, mask) ----
  int jj = tid % 48, hh = tid / 48;
  bf16x8 qb[4];  // q row (32 floats) as bf16, 16 VGPRs
  {
    const float4* qsrc = reinterpret_cast<const float4*>(proj + (size_t)(rowbase + jj) * 768 + hh * 32);
    float4 qf[8];
#pragma unroll
    for (int i = 0; i < 8; ++i) qf[i] = qsrc[i];
#pragma unroll
    for (int i = 0; i < 4; ++i) qb[i] = cvt8(qf[2 * i], qf[2 * i + 1]);
  }
#pragma unroll
  for (int it = 0; it < 8; ++it) {  // v -> LDS bf16
    int c4 = it * 384 + tid;        // 0..3071
    int j = c4 >> 6, col4 = c4 & 63;
    float4 x = *reinterpret_cast<const float4*>(proj + (size_t)(rowbase + j) * 768 + 512 + col4 * 4);
    ushort4 o;
    o.x = f2bf(x.x); o.y = f2bf(x.y); o.z = f2bf(x.z); o.w = f2bf(x.w);
    *reinterpret_cast<ushort4*>(&vbf[j * 256 + col4 * 4]) = o;
  }
#pragma unroll
  for (int it = 0; it < 4; ++it) {  // khl 6 slices
    int e = it * 384 + tid;
    int s2 = e >> 8, c = e & 255;
    khlall[s2][c] = proj[(size_t)(rowbase + k0 + s2) * 768 + 256 + c];
  }
  if (tid < KS_ * 48) maskall[tid / 48][tid % 48] = mask[(b * 48 + k0 + tid / 48) * 48 + tid % 48];

  // ---- kept-in-reg loads LAST (so prior consumption doesn't drain them) ----
  bf16x8 wf[8];
  {
    const bf16x8* wp = reinterpret_cast<const bf16x8*>(wfragm);
#pragma unroll
    for (int kt = 0; kt < 8; ++kt) wf[kt] = wp[(wave * 8 + kt) * 64 + lane];
  }
  float4 pf[8];  // triplet tile prefetch, 32 VGPRs
  {
    const float4* src = reinterpret_cast<const float4*>(trip + (size_t)(rowbase + k0) * 12288);
#pragma unroll
    for (int it = 0; it < 4; ++it) {
      int c = it * 384 + tid;
      pf[it * 2] = src[c * 2];
      pf[it * 2 + 1] = src[c * 2 + 1];
    }
  }
  bar_lgkm();

  for (int kk = 0; kk < KS_; ++kk) {
    int wg = rowbase + k0 + kk;

    // stage current tile regs -> LDS (drains pf(kk) only)
#pragma unroll
    for (int it = 0; it < 4; ++it) {
      int c = it * 384 + tid;
      int row = c >> 5;
      int off = (row << 9) + ((c & 31) << 4);
      off ^= (row & 7) << 4;
      *reinterpret_cast<bf16x8*>(tAc + off) = cvt8(pf[it * 2], pf[it * 2 + 1]);
    }
    // prefetch next slice; stays in flight across ALL phases below
    if (kk + 1 < KS_) {
      const float4* src = reinterpret_cast<const float4*>(trip + (size_t)(wg + 1) * 12288);
#pragma unroll
      for (int it = 0; it < 4; ++it) {
        int c = it * 384 + tid;
        pf[it * 2] = src[c * 2];
        pf[it * 2 + 1] = src[c * 2 + 1];
      }
    }
    bar_lgkm();  // [1] tile ready

    // GEMM (wf regs + tAc LDS; zero VMEM)
    f32x4 acc[3];
#pragma unroll
    for (int mt = 0; mt < 3; ++mt) acc[mt] = (f32x4){0.f, 0.f, 0.f, 0.f};
#pragma unroll
    for (int kt = 0; kt < 8; ++kt) {
#pragma unroll
      for (int mt = 0; mt < 3; ++mt) {
        int row = mt * 16 + (lane & 15);
        int off = (row << 9) + (kt << 6) + ((lane >> 4) << 4);
        off ^= (row & 7) << 4;
        bf16x8 a = *reinterpret_cast<const bf16x8*>(tAc + off);
        acc[mt] = __builtin_amdgcn_mfma_f32_16x16x32_bf16(a, wf[kt], acc[mt], 0, 0, 0);
      }
    }
    // epilogue: sqS[j][n] = acc + bias (j-major; 2-way banks = free)
    {
      int n = wave * 16 + (lane & 15);
      int jb = (lane >> 4) * 4;
#pragma unroll
      for (int mt = 0; mt < 3; ++mt) {
#pragma unroll
        for (int rr = 0; rr < 4; ++rr)
          sqS[(mt * 16 + jb + rr) * SQS_LD + n] = acc[mt][rr] + biasn;
      }
    }
    bar_lgkm();  // [2] sqS ready

    // scores: thread (hh,jj); q from regs, sq/sk/khl from LDS as float4
    {
      const float4* sq4 = reinterpret_cast<const float4*>(sqS + jj * SQS_LD);
      const float4* kh4 = reinterpret_cast<const float4*>(&khlall[kk][hh * 32]);
      float sc = 0.f;
#pragma unroll
      for (int d4 = 0; d4 < 8; ++d4) {
        union { bf16x8 v; unsigned u[4]; } qq;
        qq.v = qb[d4 >> 1];
        unsigned ua = qq.u[(d4 & 1) * 2], ub = qq.u[(d4 & 1) * 2 + 1];
        float4 sq = sq4[d4];
        float4 sk = sq4[8 + d4];
        float4 kh = kh4[d4];
        sc += (__uint_as_float(ua << 16) + sq.x) * (kh.x + sk.x);
        sc += (__uint_as_float(ua & 0xFFFF0000u) + sq.y) * (kh.y + sk.y);
        sc += (__uint_as_float(ub << 16) + sq.z) * (kh.z + sk.z);
        sc += (__uint_as_float(ub & 0xFFFF0000u) + sq.w) * (kh.w + sk.w);
      }
      pbuf[hh][jj] = sc * 0.17677669529663687f + maskall[kk][jj];
    }
    bar_lgkm();  // [3] scores ready

    // softmax over j per head: waves 0..5 take rows wave, wave+6
    for (int h = wave; h < 8; h += 6) {
      float x = (lane < 48) ? pbuf[h][lane] : -INFINITY;
      float m = x;
#pragma unroll
      for (int off = 32; off; off >>= 1) m = fmaxf(m, __shfl_xor(m, off));
      float e = (lane < 48) ? __expf(x - m) : 0.f;
      float sum = e;
#pragma unroll
      for (int off = 32; off; off >>= 1) sum += __shfl_xor(sum, off);
      if (lane < 48) pbuf[h][lane] = e / sum;
    }
    bar_lgkm();  // [4] probs ready

    // PV: tid<256 = (h,d); v from LDS bf16, sv from sqS; zero VMEM loads
    if (tid < 256) {
      int h = tid >> 5, d = tid & 31;
      float a = 0.f;
#pragma unroll 8
      for (int j = 0; j < 48; ++j) {
        float v = __uint_as_float((unsigned)vbf[j * 256 + tid] << 16);
        a += pbuf[h][j] * (v + sqS[j * SQS_LD + 64 + d]);
      }
      out[(size_t)wg * 256 + tid] = a;
    }
    // no trailing barrier: cvt_store(t+1) WAR on tAc is 3 barriers away
  }
}

// ---------------------------------------------------------------------------
extern "C" void kernel_launch(void* const* d_in, const int* in_sizes, int n_in,
                              void* d_out, int out_size, void* d_ws, size_t ws_size,
                              hipStream_t stream) {
  const float* mask = (const float*)d_in[0];
  const float* pair = (const float*)d_in[1];
  const float* trip = (const float*)d_in[2];
  const float* Wq = (const float*)d_in[3];
  const float* bq = (const float*)d_in[4];
  const float* Wk = (const float*)d_in[5];
  const float* bk = (const float*)d_in[6];
  const float* Wv = (const float*)d_in[7];
  const float* bv = (const float*)d_in[8];
  const float* Wsq = (const float*)d_in[9];
  const float* bsq = (const float*)d_in[10];
  const float* Wsk = (const float*)d_in[11];
  const float* bsk = (const float*)d_in[12];
  const float* Wsv = (const float*)d_in[13];
  const float* bsv = (const float*)d_in[14];

  char* ws = (char*)d_ws;
  float* proj = (float*)ws;                                               // 14,155,776 B
  unsigned short* wfrag_pair = (unsigned short*)(ws + 14155776);          // 393,216 B
  unsigned short* wfrag_main = (unsigned short*)(ws + 14155776 + 393216); // 49,152 B
  float* biascat = (float*)(ws + 14155776 + 393216 + 49152);              // 3,072 B
  float* biasm = (float*)(ws + 14155776 + 393216 + 49152 + 3072);        // 384 B

  pack_kernel<<<867, 256, 0, stream>>>(Wq, Wk, Wv, bq, bk, bv, Wsq, Wsk, Wsv,
                                       bsq, bsk, bsv,
                                       wfrag_pair, wfrag_main, biascat, biasm);
  pair_proj_kernel<<<768, 384, 0, stream>>>(pair, wfrag_pair, biascat, proj);
  e2e_main<<<768, 384, 0, stream>>>(mask, trip, proj, wfrag_main, biasm,
                                    (float*)d_out);
}

// Round 9
// 87.669 us; speedup vs baseline: 1.0772x; 1.0772x over previous
//
#include <hip/hip_runtime.h>
#include <hip/hip_bf16.h>

// Problem constants
#define B_ 2
#define N_ 48
#define H_ 256
#define NH_ 8
#define DH_ 32
#define SQS_LD 68  // sqS row stride (floats); 272B rows, 16B-aligned

typedef __attribute__((ext_vector_type(8))) short bf16x8;
typedef __attribute__((ext_vector_type(4))) float f32x4;

__device__ __forceinline__ unsigned short f2bf(float f) {
  unsigned u = __float_as_uint(f);
  u += 0x7FFFu + ((u >> 16) & 1u);
  return (unsigned short)(u >> 16);
}

// pack 8 floats -> 8 bf16 (RNE) via v_cvt_pk_bf16_f32
__device__ __forceinline__ bf16x8 cvt8(float4 x, float4 y) {
  union { unsigned u[4]; bf16x8 v; } o;
  asm("v_cvt_pk_bf16_f32 %0, %1, %2" : "=v"(o.u[0]) : "v"(x.x), "v"(x.y));
  asm("v_cvt_pk_bf16_f32 %0, %1, %2" : "=v"(o.u[1]) : "v"(x.z), "v"(x.w));
  asm("v_cvt_pk_bf16_f32 %0, %1, %2" : "=v"(o.u[2]) : "v"(y.x), "v"(y.y));
  asm("v_cvt_pk_bf16_f32 %0, %1, %2" : "=v"(o.u[3]) : "v"(y.z), "v"(y.w));
  return o.v;
}

// ---------------------------------------------------------------------------
// P0: pack weights into bf16 MFMA B-fragment order + bias concat.
// frag[nt][kt][lane][i] = W[kt*32 + (lane>>4)*8 + i][nt*16 + (lane&15)]
// ---------------------------------------------------------------------------
__global__ void pack_kernel(const float* __restrict__ Wq, const float* __restrict__ Wk,
                            const float* __restrict__ Wv, const float* __restrict__ bq,
                            const float* __restrict__ bk, const float* __restrict__ bv,
                            const float* __restrict__ Wsq, const float* __restrict__ Wsk,
                            const float* __restrict__ Wsv, const float* __restrict__ bsq,
                            const float* __restrict__ bsk, const float* __restrict__ bsv,
                            unsigned short* __restrict__ wfrag_pair,
                            unsigned short* __restrict__ wfrag_main,
                            float* __restrict__ biascat, float* __restrict__ biasm) {
  int t = blockIdx.x * 256 + threadIdx.x;
  if (t < 196608) {
    int i8 = t & 7, lane = (t >> 3) & 63, kt = (t >> 9) & 7, nt = t >> 12;
    int k = kt * 32 + ((lane >> 4) << 3) + i8;
    int n = nt * 16 + (lane & 15);
    const float* W = (n < 256) ? Wq : (n < 512) ? Wk : Wv;
    wfrag_pair[t] = f2bf(W[k * 256 + (n & 255)]);
  } else if (t < 196608 + 24576) {
    int p = t - 196608;
    int i8 = p & 7, lane = (p >> 3) & 63, kt = (p >> 9) & 7, nt = p >> 12;
    int k = kt * 32 + ((lane >> 4) << 3) + i8;
    int n = nt * 16 + (lane & 15);
    const float* W = (n < 32) ? Wsq : (n < 64) ? Wsk : Wsv;
    wfrag_main[p] = f2bf(W[k * 32 + (n & 31)]);
  } else if (t < 196608 + 24576 + 768) {
    int p = t - 196608 - 24576;
    const float* bsrc = (p < 256) ? bq : (p < 512) ? bk : bv;
    biascat[p] = bsrc[p & 255];
  } else if (t < 196608 + 24576 + 768 + 96) {
    int p = t - 196608 - 24576 - 768;
    biasm[p] = (p < 32) ? bsq[p] : (p < 64) ? bsk[p - 32] : bsv[p - 64];
  }
}

// ---------------------------------------------------------------------------
// Stage a 48x256 f32 tile -> bf16 LDS.  byte = row*512 + col*2, XOR
// ^((row&7)<<4) on both sides.
// ---------------------------------------------------------------------------
__device__ __forceinline__ void stage48x256(const float* __restrict__ src, char* tAc, int tid) {
#pragma unroll
  for (int it = 0; it < 4; ++it) {
    int c = it * 384 + tid;
    const float4* g = reinterpret_cast<const float4*>(src) + (c << 1);
    float4 x = g[0];
    float4 y = g[1];
    int row = c >> 5;
    int off = (row << 9) + ((c & 31) << 4);
    off ^= (row & 7) << 4;
    *reinterpret_cast<bf16x8*>(tAc + off) = cvt8(x, y);
  }
}

// ---------------------------------------------------------------------------
// A: pair projections.  proj[(b*48+i)*48+j][0:256]=q, [256:512]=k, [512:768]=v
// ---------------------------------------------------------------------------
__global__ __launch_bounds__(384, 3)
void pair_proj_kernel(const float* __restrict__ pair,
                      const unsigned short* __restrict__ wfrag_pair,
                      const float* __restrict__ biascat, float* __restrict__ proj) {
  __shared__ __align__(16) char tAc[48 * 256 * 2];
  int tid = threadIdx.x;
  int lane = tid & 63;
  int wave = tid >> 6;
  int gm = blockIdx.x >> 3;
  int gn = blockIdx.x & 7;

  stage48x256(pair + (size_t)gm * 12288, tAc, tid);

  bf16x8 wf[8];
  {
    const bf16x8* wp = reinterpret_cast<const bf16x8*>(wfrag_pair);
#pragma unroll
    for (int kt = 0; kt < 8; ++kt) wf[kt] = wp[((gn * 6 + wave) * 8 + kt) * 64 + lane];
  }
  __syncthreads();

  f32x4 acc[3];
#pragma unroll
  for (int mt = 0; mt < 3; ++mt) acc[mt] = (f32x4){0.f, 0.f, 0.f, 0.f};
#pragma unroll
  for (int kt = 0; kt < 8; ++kt) {
#pragma unroll
    for (int mt = 0; mt < 3; ++mt) {
      int row = mt * 16 + (lane & 15);
      int off = (row << 9) + (kt << 6) + ((lane >> 4) << 4);
      off ^= (row & 7) << 4;
      bf16x8 a = *reinterpret_cast<const bf16x8*>(tAc + off);
      acc[mt] = __builtin_amdgcn_mfma_f32_16x16x32_bf16(a, wf[kt], acc[mt], 0, 0, 0);
    }
  }

  int col = gn * 96 + wave * 16 + (lane & 15);
  float bias = biascat[col];
  int jb = (lane >> 4) * 4;
#pragma unroll
  for (int mt = 0; mt < 3; ++mt) {
#pragma unroll
    for (int rr = 0; rr < 4; ++rr) {
      int j = mt * 16 + jb + rr;
      proj[(size_t)(gm * 48 + j) * 768 + col] = acc[mt][rr] + bias;
    }
  }
}

// ---------------------------------------------------------------------------
// Fused main, LDS-traffic-minimized.  One block per (b,i,k); 4608 blocks.
//  - GEMM: waves 0-2 x 2 n-tiles (A-frag reuse 2x; B dbuf'd from L2)
//  - epilogue: waves 0-1 -> sqS[48][68] f32 (sq|sk); wave 2 -> svT bf16
//  - scores: (j, d-quad) mapping: sq/sk read ONCE, 8 h partials, shfl-reduce
//  - softmax writes pbuf f32 + pA bf16 (A-frag layout)
//  - PV: v-term vector (v from L2, p as float4 chunks); sv-term via MFMA
//    (pA @ svT -> m2buf)
// ---------------------------------------------------------------------------
__global__ __launch_bounds__(384, 6)
void e2e_fused(const float* __restrict__ mask, const float* __restrict__ trip,
               const float* __restrict__ proj, const unsigned short* __restrict__ wfragm,
               const float* __restrict__ biasm, float* __restrict__ out) {
  __shared__ __align__(16) char smem[48 * 256 * 2];      // tAc, later sqS[48][68]
  __shared__ __align__(16) unsigned short svT[32 * 64];  // 4096 B, XOR ^((d&7)<<4)
  __shared__ __align__(16) unsigned short pA[16 * 64];   // 2048 B, XOR ^((h&7)<<4)
  __shared__ float m2buf[8][32];
  __shared__ float khl[256];
  __shared__ float pbuf[8][48];
  char* tAc = smem;
  float* sqS = reinterpret_cast<float*>(smem);  // [48][SQS_LD] = 13056 B

  int tid = threadIdx.x;
  int lane = tid & 63;
  int wave = tid >> 6;

  int bid = blockIdx.x;
  int s = (bid & 7) * 576 + (bid >> 3);  // slice = (b*48+i)*48 + k
  int g = s / 48;
  int k = s % 48;
  int b = g / 48;
  int rowbase = g * 48;

  stage48x256(trip + (size_t)s * 12288, tAc, tid);
  if (tid < 256) khl[tid] = proj[(size_t)s * 768 + 256 + tid];
  {  // zero pA (512 u32) + svT (1024 u32): kills NaN risk in padded MFMA lanes
    unsigned* zp = reinterpret_cast<unsigned*>(pA);
    unsigned* zs = reinterpret_cast<unsigned*>(svT);
    zp[tid < 384 ? tid : tid] = 0;  // tid 0..383
    if (tid < 128) zp[384 + tid] = 0;
    zs[tid] = 0;
    zs[384 + tid] = 0;
    if (tid < 256) zs[768 + tid] = 0;
  }
  __syncthreads();  // [1] tile staged

  // GEMM: waves 0-2, each 2 n-tiles (n = wave*32 .. +31); B dbuf from L2
  f32x4 acc[3][2];
#pragma unroll
  for (int mt = 0; mt < 3; ++mt)
#pragma unroll
    for (int tt = 0; tt < 2; ++tt) acc[mt][tt] = (f32x4){0.f, 0.f, 0.f, 0.f};
  if (wave < 3) {
    const bf16x8* wp = reinterpret_cast<const bf16x8*>(wfragm);
    bf16x8 wc0 = wp[((wave * 2 + 0) * 8 + 0) * 64 + lane];
    bf16x8 wc1 = wp[((wave * 2 + 1) * 8 + 0) * 64 + lane];
#pragma unroll
    for (int kt = 0; kt < 8; ++kt) {
      bf16x8 wn0, wn1;
      if (kt < 7) {
        wn0 = wp[((wave * 2 + 0) * 8 + kt + 1) * 64 + lane];
        wn1 = wp[((wave * 2 + 1) * 8 + kt + 1) * 64 + lane];
      }
#pragma unroll
      for (int mt = 0; mt < 3; ++mt) {
        int row = mt * 16 + (lane & 15);
        int off = (row << 9) + (kt << 6) + ((lane >> 4) << 4);
        off ^= (row & 7) << 4;
        bf16x8 a = *reinterpret_cast<const bf16x8*>(tAc + off);
        acc[mt][0] = __builtin_amdgcn_mfma_f32_16x16x32_bf16(a, wc0, acc[mt][0], 0, 0, 0);
        acc[mt][1] = __builtin_amdgcn_mfma_f32_16x16x32_bf16(a, wc1, acc[mt][1], 0, 0, 0);
      }
      wc0 = wn0;
      wc1 = wn1;
    }
  }
  __syncthreads();  // [2] tAc reads done; smem becomes sqS

  // epilogue
  if (wave < 2) {  // sqS[j][n] = acc + bias, n = wave*32 + tt*16 + (lane&15)
    int jb = (lane >> 4) * 4;
#pragma unroll
    for (int tt = 0; tt < 2; ++tt) {
      int n = wave * 32 + tt * 16 + (lane & 15);
      float bias = biasm[n];
#pragma unroll
      for (int mt = 0; mt < 3; ++mt)
#pragma unroll
        for (int rr = 0; rr < 4; ++rr)
          sqS[(mt * 16 + jb + rr) * SQS_LD + n] = acc[mt][tt][rr] + bias;
    }
  } else if (wave == 2) {  // svT[d][j] bf16, d = tt*16 + (lane&15)
    int jb = (lane >> 4) * 4;
#pragma unroll
    for (int tt = 0; tt < 2; ++tt) {
      int d = tt * 16 + (lane & 15);
      float bias = biasm[64 + d];
#pragma unroll
      for (int mt = 0; mt < 3; ++mt)
#pragma unroll
        for (int rr = 0; rr < 4; ++rr) {
          int j = mt * 16 + jb + rr;
          int off = (d << 7) + (j << 1);
          off ^= (d & 7) << 4;
          *reinterpret_cast<unsigned short*>(reinterpret_cast<char*>(svT) + off) =
              f2bf(acc[mt][tt][rr] + bias);
        }
    }
  }
  __syncthreads();  // [3] sqS/svT ready

  // scores: thread (j = tid>>3, dq = tid&7); sq/sk read ONCE per thread
  {
    int j = tid >> 3, dq = tid & 7;
    float4 sq = *reinterpret_cast<const float4*>(sqS + j * SQS_LD + dq * 4);
    float4 sk = *reinterpret_cast<const float4*>(sqS + j * SQS_LD + 32 + dq * 4);
    const float* qrow = proj + (size_t)(rowbase + j) * 768;
    float val[8];
#pragma unroll
    for (int h = 0; h < 8; ++h) {
      float4 q = *reinterpret_cast<const float4*>(qrow + h * 32 + dq * 4);
      float4 kh = *reinterpret_cast<const float4*>(khl + h * 32 + dq * 4);
      float v = (q.x + sq.x) * (kh.x + sk.x);
      v += (q.y + sq.y) * (kh.y + sk.y);
      v += (q.z + sq.z) * (kh.z + sk.z);
      v += (q.w + sq.w) * (kh.w + sk.w);
      val[h] = v;
    }
#pragma unroll
    for (int h = 0; h < 8; ++h) {
      val[h] += __shfl_xor(val[h], 1);
      val[h] += __shfl_xor(val[h], 2);
      val[h] += __shfl_xor(val[h], 4);
    }
    float sc = val[0];
#pragma unroll
    for (int h = 1; h < 8; ++h) sc = (dq == h) ? val[h] : sc;  // static idx
    pbuf[dq][j] = sc * 0.17677669529663687f + mask[b * 2304 + k * 48 + j];
  }
  __syncthreads();  // [4] scores ready

  // softmax over j per head; write pbuf f32 + pA bf16 (A-frag layout)
  for (int h = wave; h < 8; h += 6) {
    float x = (lane < 48) ? pbuf[h][lane] : -INFINITY;
    float m = x;
#pragma unroll
    for (int off = 32; off; off >>= 1) m = fmaxf(m, __shfl_xor(m, off));
    float e = (lane < 48) ? __expf(x - m) : 0.f;
    float sum = e;
#pragma unroll
    for (int off = 32; off; off >>= 1) sum += __shfl_xor(sum, off);
    if (lane < 48) {
      float p = e / sum;
      pbuf[h][lane] = p;
      int off = (h << 7) + (lane << 1);
      off ^= (h & 7) << 4;
      *reinterpret_cast<unsigned short*>(reinterpret_cast<char*>(pA) + off) = f2bf(p);
    }
  }
  __syncthreads();  // [5] probs + pA ready

  // M2 = P @ SV via MFMA: waves 0-1 (tile = wave: d 0-15 / 16-31)
  if (wave < 2) {
    f32x4 c2 = (f32x4){0.f, 0.f, 0.f, 0.f};
#pragma unroll
    for (int ks = 0; ks < 2; ++ks) {
      int ra = ((lane & 15) << 7) + (ks << 6) + ((lane >> 4) << 4);
      ra ^= (lane & 7) << 4;  // (row&7), row = lane&15
      bf16x8 pa = *reinterpret_cast<const bf16x8*>(reinterpret_cast<char*>(pA) + ra);
      int d = (lane & 15) + wave * 16;
      int rb = (d << 7) + (ks << 6) + ((lane >> 4) << 4);
      rb ^= (d & 7) << 4;
      bf16x8 bv = *reinterpret_cast<const bf16x8*>(reinterpret_cast<char*>(svT) + rb);
      c2 = __builtin_amdgcn_mfma_f32_16x16x32_bf16(pa, bv, c2, 0, 0, 0);
    }
    if (lane < 32) {
      int h0 = (lane >> 4) * 4;
      int d = (lane & 15) + wave * 16;
#pragma unroll
      for (int r = 0; r < 4; ++r) m2buf[h0 + r][d] = c2[r];
    }
  }

  // PV vector term: v from L2, p as float4 chunks
  float a_ = 0.f;
  if (tid < 256) {
    int h = tid >> 5;
    const float* vbase = proj + (size_t)rowbase * 768 + 512 + tid;
#pragma unroll 3
    for (int j4 = 0; j4 < 12; ++j4) {
      float4 p4 = *reinterpret_cast<const float4*>(&pbuf[h][j4 * 4]);
      a_ += p4.x * vbase[(j4 * 4 + 0) * 768];
      a_ += p4.y * vbase[(j4 * 4 + 1) * 768];
      a_ += p4.z * vbase[(j4 * 4 + 2) * 768];
      a_ += p4.w * vbase[(j4 * 4 + 3) * 768];
    }
  }
  __syncthreads();  // [6] m2buf ready
  if (tid < 256) out[(size_t)s * 256 + tid] = a_ + m2buf[tid >> 5][tid & 31];
}

// ---------------------------------------------------------------------------
extern "C" void kernel_launch(void* const* d_in, const int* in_sizes, int n_in,
                              void* d_out, int out_size, void* d_ws, size_t ws_size,
                              hipStream_t stream) {
  const float* mask = (const float*)d_in[0];
  const float* pair = (const float*)d_in[1];
  const float* trip = (const float*)d_in[2];
  const float* Wq = (const float*)d_in[3];
  const float* bq = (const float*)d_in[4];
  const float* Wk = (const float*)d_in[5];
  const float* bk = (const float*)d_in[6];
  const float* Wv = (const float*)d_in[7];
  const float* bv = (const float*)d_in[8];
  const float* Wsq = (const float*)d_in[9];
  const float* bsq = (const float*)d_in[10];
  const float* Wsk = (const float*)d_in[11];
  const float* bsk = (const float*)d_in[12];
  const float* Wsv = (const float*)d_in[13];
  const float* bsv = (const float*)d_in[14];

  char* ws = (char*)d_ws;
  float* proj = (float*)ws;                                               // 14,155,776 B
  unsigned short* wfrag_pair = (unsigned short*)(ws + 14155776);          // 393,216 B
  unsigned short* wfrag_main = (unsigned short*)(ws + 14155776 + 393216); // 49,152 B
  float* biascat = (float*)(ws + 14155776 + 393216 + 49152);              // 3,072 B
  float* biasm = (float*)(ws + 14155776 + 393216 + 49152 + 3072);        // 384 B

  pack_kernel<<<867, 256, 0, stream>>>(Wq, Wk, Wv, bq, bk, bv, Wsq, Wsk, Wsv,
                                       bsq, bsk, bsv,
                                       wfrag_pair, wfrag_main, biascat, biasm);
  pair_proj_kernel<<<768, 384, 0, stream>>>(pair, wfrag_pair, biascat, proj);
  e2e_fused<<<4608, 384, 0, stream>>>(mask, trip, proj, wfrag_main, biasm,
                                      (float*)d_out);
}

// Round 10
// 72.477 us; speedup vs baseline: 1.3030x; 1.2096x over previous
//
#include <hip/hip_runtime.h>
#include <hip/hip_bf16.h>

// Problem constants
#define B_ 2
#define N_ 48
#define H_ 256
#define NH_ 8
#define DH_ 32
#define SQS_LD 100  // sqS row stride in floats (400B, 16B-aligned)

typedef __attribute__((ext_vector_type(8))) short bf16x8;
typedef __attribute__((ext_vector_type(4))) float f32x4;

__device__ __forceinline__ unsigned short f2bf(float f) {
  unsigned u = __float_as_uint(f);
  u += 0x7FFFu + ((u >> 16) & 1u);
  return (unsigned short)(u >> 16);
}

// pack 8 floats -> 8 bf16 (RNE) via v_cvt_pk_bf16_f32
__device__ __forceinline__ bf16x8 cvt8(float4 x, float4 y) {
  union { unsigned u[4]; bf16x8 v; } o;
  asm("v_cvt_pk_bf16_f32 %0, %1, %2" : "=v"(o.u[0]) : "v"(x.x), "v"(x.y));
  asm("v_cvt_pk_bf16_f32 %0, %1, %2" : "=v"(o.u[1]) : "v"(x.z), "v"(x.w));
  asm("v_cvt_pk_bf16_f32 %0, %1, %2" : "=v"(o.u[2]) : "v"(y.x), "v"(y.y));
  asm("v_cvt_pk_bf16_f32 %0, %1, %2" : "=v"(o.u[3]) : "v"(y.z), "v"(y.w));
  return o.v;
}

// Raw barrier WITHOUT vmcnt drain (keeps global loads in flight across it)
__device__ __forceinline__ void bar_lgkm() {
  asm volatile("s_waitcnt lgkmcnt(0)" ::: "memory");
  __builtin_amdgcn_s_barrier();
  asm volatile("" ::: "memory");
}

// ---------------------------------------------------------------------------
// Stage a 48x256 f32 tile -> bf16 LDS (row-split chunks).
// byte = row*512 + col*2, XOR ^((row&7)<<4) both sides.
// ---------------------------------------------------------------------------
__device__ __forceinline__ void stage48x256(const float* __restrict__ src, char* tAc, int tid) {
#pragma unroll
  for (int it = 0; it < 4; ++it) {
    int c = it * 384 + tid;
    const float4* g = reinterpret_cast<const float4*>(src) + (c << 1);
    float4 x = g[0];
    float4 y = g[1];
    int row = c >> 5;
    int off = (row << 9) + ((c & 31) << 4);
    off ^= (row & 7) << 4;
    *reinterpret_cast<bf16x8*>(tAc + off) = cvt8(x, y);
  }
}

// ---------------------------------------------------------------------------
// Pair projections (self-packing; no pack_kernel).
// Outputs planes: qplane bf16 [4608][256], kplane f32 [4608][256],
// vplane bf16 [4608][256].  gn==7 blocks also side-pack wfrag_main + biasm
// for the e2e kernel (launched afterwards).
// ---------------------------------------------------------------------------
__global__ __launch_bounds__(384, 3)
void pair_proj_kernel(const float* __restrict__ pair,
                      const float* __restrict__ Wq, const float* __restrict__ Wk,
                      const float* __restrict__ Wv, const float* __restrict__ bq,
                      const float* __restrict__ bk, const float* __restrict__ bv,
                      const float* __restrict__ Wsq, const float* __restrict__ Wsk,
                      const float* __restrict__ Wsv, const float* __restrict__ bsq,
                      const float* __restrict__ bsk, const float* __restrict__ bsv,
                      unsigned short* __restrict__ qplane, float* __restrict__ kplane,
                      unsigned short* __restrict__ vplane,
                      unsigned short* __restrict__ wfrag_main, float* __restrict__ biasm) {
  __shared__ __align__(16) char tAc[48 * 256 * 2];
  int tid = threadIdx.x;
  int lane = tid & 63;
  int wave = tid >> 6;
  int gm = blockIdx.x >> 3;  // (b,i) group
  int gn = blockIdx.x & 7;   // 96-col group

  stage48x256(pair + (size_t)gm * 12288, tAc, tid);

  // self-pack this wave's B-fragments from W (L2-hot; strip is in ONE matrix
  // since n0 is a multiple of 16 and boundaries are at 256/512)
  int col = gn * 96 + wave * 16 + (lane & 15);
  const float* Wsel = (col < 256) ? Wq : (col < 512) ? Wk : Wv;
  const float* bsel = (col < 256) ? bq : (col < 512) ? bk : bv;
  int cc = col & 255;
  bf16x8 wf[8];
#pragma unroll
  for (int kt = 0; kt < 8; ++kt) {
    int kbase = kt * 32 + ((lane >> 4) << 3);
    float4 w0, w1;
    w0.x = Wsel[(kbase + 0) * 256 + cc];
    w0.y = Wsel[(kbase + 1) * 256 + cc];
    w0.z = Wsel[(kbase + 2) * 256 + cc];
    w0.w = Wsel[(kbase + 3) * 256 + cc];
    w1.x = Wsel[(kbase + 4) * 256 + cc];
    w1.y = Wsel[(kbase + 5) * 256 + cc];
    w1.z = Wsel[(kbase + 6) * 256 + cc];
    w1.w = Wsel[(kbase + 7) * 256 + cc];
    wf[kt] = cvt8(w0, w1);
  }
  float bias = bsel[cc];

  // side-pack wfrag_main (96 gn==7 blocks x 256 entries) + biasm
  if (gn == 7) {
    if (tid < 256) {
      int p = gm * 256 + tid;
      int i8 = p & 7, l2 = (p >> 3) & 63, kt2 = (p >> 9) & 7, nt2 = p >> 12;
      int k2 = kt2 * 32 + ((l2 >> 4) << 3) + i8;
      int n2 = nt2 * 16 + (l2 & 15);
      const float* W = (n2 < 32) ? Wsq : (n2 < 64) ? Wsk : Wsv;
      wfrag_main[p] = f2bf(W[k2 * 32 + (n2 & 31)]);
    } else if (gm == 0 && tid < 352) {
      int p = tid - 256;
      biasm[p] = (p < 32) ? bsq[p] : (p < 64) ? bsk[p - 32] : bsv[p - 64];
    }
  }
  __syncthreads();

  f32x4 acc[3];
#pragma unroll
  for (int mt = 0; mt < 3; ++mt) acc[mt] = (f32x4){0.f, 0.f, 0.f, 0.f};
#pragma unroll
  for (int kt = 0; kt < 8; ++kt) {
#pragma unroll
    for (int mt = 0; mt < 3; ++mt) {
      int row = mt * 16 + (lane & 15);
      int off = (row << 9) + (kt << 6) + ((lane >> 4) << 4);
      off ^= (row & 7) << 4;
      bf16x8 a = *reinterpret_cast<const bf16x8*>(tAc + off);
      acc[mt] = __builtin_amdgcn_mfma_f32_16x16x32_bf16(a, wf[kt], acc[mt], 0, 0, 0);
    }
  }

  int jb = (lane >> 4) * 4;
#pragma unroll
  for (int mt = 0; mt < 3; ++mt) {
#pragma unroll
    for (int rr = 0; rr < 4; ++rr) {
      int j = mt * 16 + jb + rr;
      size_t row = (size_t)(gm * 48 + j) * 256;
      float val = acc[mt][rr] + bias;
      if (col < 256) qplane[row + col] = f2bf(val);
      else if (col < 512) kplane[row + (col - 256)] = val;
      else vplane[row + (col - 512)] = f2bf(val);
    }
  }
}

// ---------------------------------------------------------------------------
// Fused main (R7 structure + bf16 q/v planes + K-split double-stage).
// One block per (b,i,k); 4608 blocks.  LDS 27.1KB, VGPR-lean.
// Stage cols 0-127 -> bar -> GEMM kt0-3 (cols 128-255 loads still in
// flight) -> write half2 -> bar -> GEMM kt4-7 -> bar -> epilogue(sqS,
// j-major f32) -> bar -> scores -> bar -> softmax -> bar -> PV.
// XCD swizzle: same-(b,i) slices share an XCD for q/v L2 reuse.
// ---------------------------------------------------------------------------
__global__ __launch_bounds__(384, 6)
void e2e_fused(const float* __restrict__ mask, const float* __restrict__ trip,
               const unsigned short* __restrict__ qplane, const float* __restrict__ kplane,
               const unsigned short* __restrict__ vplane,
               const unsigned short* __restrict__ wfragm,
               const float* __restrict__ biasm, float* __restrict__ out) {
  __shared__ __align__(16) char smem[48 * 256 * 2];  // tAc, later sqS[48][100]
  __shared__ float khl[256];
  __shared__ float pbuf[8][48];
  char* tAc = smem;
  float* sqS = reinterpret_cast<float*>(smem);  // [48][SQS_LD] = 19200 B

  int tid = threadIdx.x;
  int lane = tid & 63;
  int wave = tid >> 6;

  int bid = blockIdx.x;
  int s = (bid & 7) * 576 + (bid >> 3);  // slice = (b*48+i)*48 + k
  int g = s / 48;
  int k = s % 48;
  int b = g / 48;
  int rowbase = g * 48;

  // k-row (f32) for this slice
  if (tid < 256) khl[tid] = kplane[(size_t)s * 256 + tid];

  // K-split staged load: half1 = cols 0-127, half2 = cols 128-255.
  // chunk c in [0,768): row = c>>4 (0..47), colc = c&15 (16B bf16 chunks)
  const float4* src = reinterpret_cast<const float4*>(trip + (size_t)s * 12288);
  int r0 = tid >> 4, c0 = tid & 15;          // it 0: c = tid
  int r1 = (384 + tid) >> 4, c1 = tid & 15;  // it 1: c = 384+tid
  float4 pa[4], pb[4];
  pa[0] = src[r0 * 64 + c0 * 2];
  pa[1] = src[r0 * 64 + c0 * 2 + 1];
  pa[2] = src[r1 * 64 + c1 * 2];
  pa[3] = src[r1 * 64 + c1 * 2 + 1];
  pb[0] = src[r0 * 64 + 32 + c0 * 2];
  pb[1] = src[r0 * 64 + 32 + c0 * 2 + 1];
  pb[2] = src[r1 * 64 + 32 + c1 * 2];
  pb[3] = src[r1 * 64 + 32 + c1 * 2 + 1];

  {  // write half1 (compiler waits only on pa's loads)
    int off0 = (r0 << 9) + (c0 << 4);
    off0 ^= (r0 & 7) << 4;
    *reinterpret_cast<bf16x8*>(tAc + off0) = cvt8(pa[0], pa[1]);
    int off1 = (r1 << 9) + (c1 << 4);
    off1 ^= (r1 & 7) << 4;
    *reinterpret_cast<bf16x8*>(tAc + off1) = cvt8(pa[2], pa[3]);
  }
  bar_lgkm();  // [1] half1 staged; pb loads still in flight

  // GEMM kt0-3 (cols 0-127); B-frags from L2 per kt
  const bf16x8* wp = reinterpret_cast<const bf16x8*>(wfragm);
  f32x4 acc[3];
#pragma unroll
  for (int mt = 0; mt < 3; ++mt) acc[mt] = (f32x4){0.f, 0.f, 0.f, 0.f};
#pragma unroll
  for (int kt = 0; kt < 4; ++kt) {
    bf16x8 w = wp[(wave * 8 + kt) * 64 + lane];
#pragma unroll
    for (int mt = 0; mt < 3; ++mt) {
      int row = mt * 16 + (lane & 15);
      int off = (row << 9) + (kt << 6) + ((lane >> 4) << 4);
      off ^= (row & 7) << 4;
      bf16x8 a = *reinterpret_cast<const bf16x8*>(tAc + off);
      acc[mt] = __builtin_amdgcn_mfma_f32_16x16x32_bf16(a, w, acc[mt], 0, 0, 0);
    }
  }
  {  // write half2
    int off0 = (r0 << 9) + ((16 + c0) << 4);
    off0 ^= (r0 & 7) << 4;
    *reinterpret_cast<bf16x8*>(tAc + off0) = cvt8(pb[0], pb[1]);
    int off1 = (r1 << 9) + ((16 + c1) << 4);
    off1 ^= (r1 & 7) << 4;
    *reinterpret_cast<bf16x8*>(tAc + off1) = cvt8(pb[2], pb[3]);
  }
  bar_lgkm();  // [2] half2 staged

#pragma unroll
  for (int kt = 4; kt < 8; ++kt) {
    bf16x8 w = wp[(wave * 8 + kt) * 64 + lane];
#pragma unroll
    for (int mt = 0; mt < 3; ++mt) {
      int row = mt * 16 + (lane & 15);
      int off = (row << 9) + (kt << 6) + ((lane >> 4) << 4);
      off ^= (row & 7) << 4;
      bf16x8 a = *reinterpret_cast<const bf16x8*>(tAc + off);
      acc[mt] = __builtin_amdgcn_mfma_f32_16x16x32_bf16(a, w, acc[mt], 0, 0, 0);
    }
  }
  bar_lgkm();  // [3] tAc reads done; smem becomes sqS

  // epilogue: sqS[j][n] = acc + bias (j-major)
  {
    int n = wave * 16 + (lane & 15);
    float bias = biasm[n];
    int jb = (lane >> 4) * 4;
#pragma unroll
    for (int mt = 0; mt < 3; ++mt) {
#pragma unroll
      for (int rr = 0; rr < 4; ++rr)
        sqS[(mt * 16 + jb + rr) * SQS_LD + n] = acc[mt][rr] + bias;
    }
  }
  bar_lgkm();  // [4] sqS ready

  // scores: thread (h = tid/48, j = tid%48); q bf16 from qplane, sq/sk/khl
  // from LDS as float4
  {
    int j = tid % 48, h = tid / 48;
    const uint4* qp = reinterpret_cast<const uint4*>(qplane + (size_t)(rowbase + j) * 256 + h * 32);
    const float4* sq4 = reinterpret_cast<const float4*>(sqS + j * SQS_LD);
    const float4* kh4 = reinterpret_cast<const float4*>(khl + h * 32);
    float sc = 0.f;
#pragma unroll
    for (int q4i = 0; q4i < 4; ++q4i) {  // 8 cols per iter
      uint4 qw = qp[q4i];
      float4 sqA = sq4[q4i * 2], sqB = sq4[q4i * 2 + 1];
      float4 skA = sq4[8 + q4i * 2], skB = sq4[8 + q4i * 2 + 1];
      float4 khA = kh4[q4i * 2], khB = kh4[q4i * 2 + 1];
      sc += (__uint_as_float(qw.x << 16) + sqA.x) * (khA.x + skA.x);
      sc += (__uint_as_float(qw.x & 0xFFFF0000u) + sqA.y) * (khA.y + skA.y);
      sc += (__uint_as_float(qw.y << 16) + sqA.z) * (khA.z + skA.z);
      sc += (__uint_as_float(qw.y & 0xFFFF0000u) + sqA.w) * (khA.w + skA.w);
      sc += (__uint_as_float(qw.z << 16) + sqB.x) * (khB.x + skB.x);
      sc += (__uint_as_float(qw.z & 0xFFFF0000u) + sqB.y) * (khB.y + skB.y);
      sc += (__uint_as_float(qw.w << 16) + sqB.z) * (khB.z + skB.z);
      sc += (__uint_as_float(qw.w & 0xFFFF0000u) + sqB.w) * (khB.w + skB.w);
    }
    pbuf[h][j] = sc * 0.17677669529663687f + mask[b * 2304 + k * 48 + j];
  }
  bar_lgkm();  // [5] scores ready

  // softmax over j per head: waves 0..5 take rows wave, wave+6
  for (int h = wave; h < 8; h += 6) {
    float x = (lane < 48) ? pbuf[h][lane] : -INFINITY;
    float m = x;
#pragma unroll
    for (int off = 32; off; off >>= 1) m = fmaxf(m, __shfl_xor(m, off));
    float e = (lane < 48) ? __expf(x - m) : 0.f;
    float sum = e;
#pragma unroll
    for (int off = 32; off; off >>= 1) sum += __shfl_xor(sum, off);
    if (lane < 48) pbuf[h][lane] = e / sum;
  }
  bar_lgkm();  // [6] probs ready

  // PV: tid<256 = (h,d); v bf16 from vplane, sv from sqS
  if (tid < 256) {
    int h = tid >> 5, d = tid & 31;
    const unsigned short* vbase = vplane + (size_t)rowbase * 256 + tid;
    float a = 0.f;
#pragma unroll 8
    for (int j = 0; j < 48; ++j) {
      float v = __uint_as_float((unsigned)vbase[(size_t)j * 256] << 16);
      a += pbuf[h][j] * (v + sqS[j * SQS_LD + 64 + d]);
    }
    out[(size_t)s * 256 + tid] = a;
  }
}

// ---------------------------------------------------------------------------
extern "C" void kernel_launch(void* const* d_in, const int* in_sizes, int n_in,
                              void* d_out, int out_size, void* d_ws, size_t ws_size,
                              hipStream_t stream) {
  const float* mask = (const float*)d_in[0];
  const float* pair = (const float*)d_in[1];
  const float* trip = (const float*)d_in[2];
  const float* Wq = (const float*)d_in[3];
  const float* bq = (const float*)d_in[4];
  const float* Wk = (const float*)d_in[5];
  const float* bk = (const float*)d_in[6];
  const float* Wv = (const float*)d_in[7];
  const float* bv = (const float*)d_in[8];
  const float* Wsq = (const float*)d_in[9];
  const float* bsq = (const float*)d_in[10];
  const float* Wsk = (const float*)d_in[11];
  const float* bsk = (const float*)d_in[12];
  const float* Wsv = (const float*)d_in[13];
  const float* bsv = (const float*)d_in[14];

  char* ws = (char*)d_ws;
  unsigned short* qplane = (unsigned short*)ws;              // 2,359,296 B
  float* kplane = (float*)(ws + 2359296);                    // 4,718,592 B
  unsigned short* vplane = (unsigned short*)(ws + 7077888);  // 2,359,296 B
  unsigned short* wfrag_main = (unsigned short*)(ws + 9437184);  // 49,152 B
  float* biasm = (float*)(ws + 9486336);                     // 384 B

  pair_proj_kernel<<<768, 384, 0, stream>>>(pair, Wq, Wk, Wv, bq, bk, bv,
                                            Wsq, Wsk, Wsv, bsq, bsk, bsv,
                                            qplane, kplane, vplane,
                                            wfrag_main, biasm);
  e2e_fused<<<4608, 384, 0, stream>>>(mask, trip, qplane, kplane, vplane,
                                      wfrag_main, biasm, (float*)d_out);
}